// Round 9
// baseline (1601.726 us; speedup 1.0000x reference)
//
#include <hip/hip_runtime.h>
#include <hip/hip_bf16.h>

#define D_MODEL 768
#define SEQ     1024
#define NB      8
#define NHEAD   12
#define HS      64
#define NLAYER  4
#define DFF     3072
#define NCLS    16
#define MROWS   (NB*SEQ)   // 8192

typedef float f32x4  __attribute__((ext_vector_type(4)));
typedef short bf16x8 __attribute__((ext_vector_type(8)));

__device__ __forceinline__ short f2bf_s(float x) {
    __hip_bfloat16 h = __float2bfloat16(x);
    union { __hip_bfloat16 h; short s; } u; u.h = h; return u.s;
}

// async global->LDS, 16B per lane; lds base must be wave-uniform (HW adds lane*16)
__device__ __forceinline__ void gld16(const void* g, void* l) {
    __builtin_amdgcn_global_load_lds((const __attribute__((address_space(1))) void*)g,
                                     (__attribute__((address_space(3))) void*)l, 16, 0, 0);
}

// ---------------------------------------------------------------- embedding
// one row per WAVE: 12 f32/lane via float4, no LDS/barriers. grid = MROWS/4.
__global__ __launch_bounds__(256) void embed_kernel(
    const int* __restrict__ x, const float* __restrict__ tok,
    const float* __restrict__ pos, float* __restrict__ h)
{
    int wave = threadIdx.x >> 6, lane = threadIdx.x & 63;
    int row = blockIdx.x * 4 + wave;
    int s   = row & (SEQ - 1);
    int id  = x[row];
    const float4* te = (const float4*)(tok + (size_t)id * D_MODEL);
    const float4* pe = (const float4*)(pos + (size_t)s  * D_MODEL);
    float4* hr = (float4*)(h + (size_t)row * D_MODEL);
    #pragma unroll
    for (int j = 0; j < 3; j++) {
        float4 a = te[j * 64 + lane], p = pe[j * 64 + lane];
        a.x += p.x; a.y += p.y; a.z += p.z; a.w += p.w;
        hr[j * 64 + lane] = a;
    }
}

// ---------------------------------------------------------------- layernorm
// one row per WAVE (4 rows/block): float4 loads, full-wave shfl_xor reduce,
// ZERO LDS / barriers. grid = rows/4.
template<int BF16OUT>
__global__ __launch_bounds__(256) void ln_kernel(
    const float* __restrict__ in, const float* __restrict__ w,
    const float* __restrict__ b, void* __restrict__ outv,
    int row_stride, int row_offset)
{
    int wave = threadIdx.x >> 6, lane = threadIdx.x & 63;
    int r = blockIdx.x * 4 + wave;
    const float4* xr = (const float4*)(in + (size_t)(r * row_stride + row_offset) * D_MODEL);
    float4 v0 = xr[lane], v1 = xr[64 + lane], v2 = xr[128 + lane];
    float s = v0.x + v0.y + v0.z + v0.w
            + v1.x + v1.y + v1.z + v1.w
            + v2.x + v2.y + v2.z + v2.w;
    #pragma unroll
    for (int off = 32; off; off >>= 1) s += __shfl_xor(s, off);
    float mu = s * (1.f / D_MODEL);
    float4 d0, d1, d2;
    d0.x = v0.x - mu; d0.y = v0.y - mu; d0.z = v0.z - mu; d0.w = v0.w - mu;
    d1.x = v1.x - mu; d1.y = v1.y - mu; d1.z = v1.z - mu; d1.w = v1.w - mu;
    d2.x = v2.x - mu; d2.y = v2.y - mu; d2.z = v2.z - mu; d2.w = v2.w - mu;
    float q = d0.x*d0.x + d0.y*d0.y + d0.z*d0.z + d0.w*d0.w
            + d1.x*d1.x + d1.y*d1.y + d1.z*d1.z + d1.w*d1.w
            + d2.x*d2.x + d2.y*d2.y + d2.z*d2.z + d2.w*d2.w;
    #pragma unroll
    for (int off = 32; off; off >>= 1) q += __shfl_xor(q, off);
    float rstd = rsqrtf(q * (1.f / D_MODEL) + 1e-5f);
    const float4* w4 = (const float4*)w;
    const float4* b4 = (const float4*)b;
    float4 dd[3] = {d0, d1, d2};
    if (BF16OUT) {
        short* yr = (short*)outv + (size_t)r * D_MODEL;
        #pragma unroll
        for (int j = 0; j < 3; j++) {
            float4 ww = w4[j * 64 + lane], bb = b4[j * 64 + lane];
            union { uint2 u; short s[4]; } pk;
            pk.s[0] = f2bf_s(dd[j].x * rstd * ww.x + bb.x);
            pk.s[1] = f2bf_s(dd[j].y * rstd * ww.y + bb.y);
            pk.s[2] = f2bf_s(dd[j].z * rstd * ww.z + bb.z);
            pk.s[3] = f2bf_s(dd[j].w * rstd * ww.w + bb.w);
            *(uint2*)(yr + j * 256 + lane * 4) = pk.u;
        }
    } else {
        float4* yr = (float4*)((float*)outv + (size_t)r * D_MODEL);
        #pragma unroll
        for (int j = 0; j < 3; j++) {
            float4 ww = w4[j * 64 + lane], bb = b4[j * 64 + lane];
            float4 y;
            y.x = dd[j].x * rstd * ww.x + bb.x;
            y.y = dd[j].y * rstd * ww.y + bb.y;
            y.z = dd[j].z * rstd * ww.z + bb.z;
            y.w = dd[j].w * rstd * ww.w + bb.w;
            yr[j * 64 + lane] = y;
        }
    }
}

// --------------------------------------------- weight convert+transpose to bf16
template<int MODE>
__global__ __launch_bounds__(256) void convw_kernel(
    const float* __restrict__ W, __hip_bfloat16* __restrict__ BT,
    int K, int N, size_t in_stride, size_t out_stride)
{
    __shared__ __hip_bfloat16 sT[64][72];
    W  += (size_t)blockIdx.z * in_stride;
    BT += (size_t)blockIdx.z * out_stride;
    int k0 = blockIdx.x * 64, n0 = blockIdx.y * 64;
    int t = threadIdx.x;
    int kl = t >> 4, nl4 = (t & 15) * 4;
    #pragma unroll
    for (int i = 0; i < 4; i++) {
        int k = k0 + kl + i * 16;
        int n = n0 + nl4;
        const float* src = (MODE == 0) ? (W + (size_t)k * N + n)
                                       : (W + ((size_t)(n >> 6) * K + k) * 64 + (n & 63));
        float4 v = *(const float4*)src;
        sT[nl4 + 0][kl + i*16] = __float2bfloat16(v.x);
        sT[nl4 + 1][kl + i*16] = __float2bfloat16(v.y);
        sT[nl4 + 2][kl + i*16] = __float2bfloat16(v.z);
        sT[nl4 + 3][kl + i*16] = __float2bfloat16(v.w);
    }
    __syncthreads();
    int nl = t >> 2, seg = (t & 3) * 16;
    uint4* dst = (uint4*)(BT + (size_t)(n0 + nl) * K + k0 + seg);
    dst[0] = *(uint4*)&sT[nl][seg];
    dst[1] = *(uint4*)&sT[nl][seg + 8];
}

// ---------------------------------------------------------------- bf16 MFMA GEMM
// 128x128 tile, 8 waves (2M x 4N wave grid), 2 LDS buffers (32 KB) ->
// 4 blocks/CU -> 32 waves/CU (8/SIMD, full wave slots). VGPR=40 permits it.
// Schedule per K-step: vmcnt(0) [own stage(t) done; drain covered by 8-wave TLP]
// -> barrier [all waves' stage(t) visible] -> ds_read frags -> STAGE(t+1) -> MFMA.
// WAR: stage(t+1) overwrites buf[(t-1)&1]; every wave finished reading it before
// its iter t-1 MFMAs issued (operand waits), hence before the iter-t barrier.
// OMODE: 0 = f32 out (+bias,+res)   1 = QKV scatter (V third written TRANSPOSED
//        to (bh,e,s) with packed uint2 stores)   2 = bf16 out
//        3 = split-K over blockIdx.z, atomicAdd f32 into C
template<int OMODE>
__global__ __launch_bounds__(512, 8) void gemm128(
    const __hip_bfloat16* __restrict__ A, const __hip_bfloat16* __restrict__ BT,
    const float* __restrict__ bias, const float* __restrict__ res,
    void* __restrict__ Cv, int M, int N, int K, int relu)
{
    __shared__ short sA[2][128 * 32];
    __shared__ short sB[2][128 * 32];
    int t = threadIdx.x;
    int wave = t >> 6, lane = t & 63;
    int l16 = lane & 15, quad = (lane >> 4) & 3;
    int wm = wave >> 2, wn = wave & 3;          // 2M x 4N wave grid
    int bm = blockIdx.x * 128, bn = blockIdx.y * 128;

    int kbeg = 0, kend = K;
    if (OMODE == 3) { int KS = K >> 1; kbeg = blockIdx.z * KS; kend = kbeg + KS; }
    int nsteps = (kend - kbeg) >> 5;

    int u = lane >> 2;
    int skey = ((u & 3) ^ ((u >> 2) & 3));
    int sseg = (lane & 3) ^ skey;
    int fkey = ((l16 & 3) ^ ((l16 >> 2) & 3));

    const f32x4 zf = {0.f, 0.f, 0.f, 0.f};
    f32x4 acc[4][2];
    #pragma unroll
    for (int mi = 0; mi < 4; mi++)
        #pragma unroll
        for (int ni = 0; ni < 2; ni++) acc[mi][ni] = zf;

    // each wave stages chunk 'wave' (16 rows) of A and of B
    const __hip_bfloat16* pA = A  + (size_t)(bm + (wave << 4) + u) * K + kbeg + sseg * 8;
    const __hip_bfloat16* pB = BT + (size_t)(bn + (wave << 4) + u) * K + kbeg + sseg * 8;

    #define STAGE(bufi, kk) do { \
        gld16(pA + (kk), &sA[bufi][wave * 512]); \
        gld16(pB + (kk), &sB[bufi][wave * 512]); \
    } while (0)

    STAGE(0, 0);

    for (int it = 0; it < nsteps; ++it) {
        asm volatile("s_waitcnt vmcnt(0)" ::: "memory");   // own stage(t) landed
        __builtin_amdgcn_sched_barrier(0);
        __builtin_amdgcn_s_barrier();                      // all waves' stage(t) visible
        __builtin_amdgcn_sched_barrier(0);

        const short* curA = &sA[it & 1][0];
        const short* curB = &sB[it & 1][0];
        bf16x8 aF[4], bF[2];
        #pragma unroll
        for (int mi = 0; mi < 4; mi++)
            aF[mi] = *(const bf16x8*)&curA[(wm * 64 + mi * 16 + l16) * 32 + ((quad ^ fkey) * 8)];
        #pragma unroll
        for (int ni = 0; ni < 2; ni++)
            bF[ni] = *(const bf16x8*)&curB[(wn * 32 + ni * 16 + l16) * 32 + ((quad ^ fkey) * 8)];

        if (it + 1 < nsteps) STAGE((it + 1) & 1, (it + 1) * 32);   // prefetch next

        // compiler-managed counted lgkm waits; all frags consumed below, so this
        // wave's ds_reads complete before it reaches the next barrier (WAR ok).
        #pragma unroll
        for (int ni = 0; ni < 2; ni++)
            #pragma unroll
            for (int mi = 0; mi < 4; mi++)
                acc[mi][ni] = __builtin_amdgcn_mfma_f32_16x16x32_bf16(aF[mi], bF[ni], acc[mi][ni], 0, 0, 0);
    }
    #undef STAGE

    #pragma unroll
    for (int mi = 0; mi < 4; mi++) {
        #pragma unroll
        for (int ni = 0; ni < 2; ni++) {
            int row0 = bm + wm * 64 + mi * 16 + quad * 4;
            int col  = bn + wn * 32 + ni * 16 + l16;
            if (OMODE == 1) {
                // QKV scatter. row0 % 4 == 0, rows row0..row0+3 share bb.
                int which = col / D_MODEL, cc = col % D_MODEL;
                int hh = cc >> 6, e = cc & 63;
                int bb = row0 >> 10, ss0 = row0 & 1023;
                union { uint2 u; short s[4]; } pk;
                #pragma unroll
                for (int r = 0; r < 4; r++) pk.s[r] = f2bf_s(acc[mi][ni][r]);
                __hip_bfloat16* dstb = (__hip_bfloat16*)Cv + (size_t)which * MROWS * D_MODEL;
                if (which == 2) {
                    // V -> (bh, e, s) transposed; 4 consecutive s -> one uint2
                    *(uint2*)(dstb + ((size_t)(bb * NHEAD + hh)) * HS * SEQ + (size_t)e * SEQ + ss0) = pk.u;
                } else {
                    short* p = (short*)(dstb + (((size_t)(bb * NHEAD + hh)) * SEQ + ss0) * HS + e);
                    #pragma unroll
                    for (int r = 0; r < 4; r++) p[r * HS] = pk.s[r];
                }
                continue;
            }
            #pragma unroll
            for (int r = 0; r < 4; r++) {
                int row = row0 + r;
                float v = acc[mi][ni][r];
                if (OMODE == 3) {
                    float* C = (float*)Cv;
                    if (blockIdx.z == 0 && bias) v += bias[col];
                    unsafeAtomicAdd(&C[(size_t)row * N + col], v);
                    continue;
                }
                if (bias) v += bias[col];
                if (relu) v = fmaxf(v, 0.f);
                if (OMODE == 0) {
                    float* C = (float*)Cv;
                    if (res) v += res[(size_t)row * N + col];
                    C[(size_t)row * N + col] = v;
                } else {
                    ((__hip_bfloat16*)Cv)[(size_t)row * N + col] = __float2bfloat16(v);
                }
            }
        }
    }
    (void)M;
}

// ---------------------------------------------------------------- MFMA flash attention (S^T orientation)
// Block = 4 waves = 256 queries of one (b,h); wave owns 64 queries (4 qt-tiles).
// K/VT staging shared by all 4 waves (each wave stages 2 of 8 column-groups).
// XCD-bijective remap keeps the 4 q-blocks of one (b,h) on one XCD (K/VT L2-local).
__global__ __launch_bounds__(256, 2) void attn_mfma_kernel(
    const __hip_bfloat16* __restrict__ q, const __hip_bfloat16* __restrict__ k,
    const __hip_bfloat16* __restrict__ v, const int* __restrict__ mask,
    __hip_bfloat16* __restrict__ ao)
{
    __shared__ short sK[2][64 * 64];
    __shared__ short sVT[2][64 * 64];
    __shared__ short sP[4][64 * 64];
    __shared__ float mskf[SEQ];
    int bid = blockIdx.x;                 // 384 = 8 XCD x 48
    int xcd = bid & 7, j = bid >> 3;      // j in 0..47
    int bh  = ((j >> 2) << 3) | xcd;      // bijective: bh in 0..95
    int qt4 = j & 3;
    int b = bh / NHEAD, hh = bh % NHEAD;
    int t = threadIdx.x, w = t >> 6, lane = t & 63;
    int l16 = lane & 15, quad = lane >> 4;
    const float scale = 0.036084391824351615f;  // 768^-0.5
    const f32x4 zf = {0.f, 0.f, 0.f, 0.f};

    #pragma unroll
    for (int i = 0; i < 4; i++) {
        int idx = t + i * 256;
        mskf[idx] = mask[b * SEQ + idx] ? 0.f : -1e30f;
    }

    // Q B-frags: lane n=query(l16), k=dim s*32+quad*8..+7
    int qb0 = qt4 * 256 + w * 64;
    const __hip_bfloat16* qbase = q + ((size_t)bh * SEQ + qb0) * HS;
    bf16x8 qf[4][2];
    #pragma unroll
    for (int qt = 0; qt < 4; qt++)
        #pragma unroll
        for (int s = 0; s < 2; s++)
            qf[qt][s] = *(const bf16x8*)(qbase + (qt * 16 + l16) * HS + s * 32 + quad * 8);

    f32x4 accO[4][4];            // [dt][qt]: O^T tile, row=dim dt*16+quad*4+r, col=query qt*16+l16
    float m_st[4], l_st[4];
    #pragma unroll
    for (int dt = 0; dt < 4; dt++)
        #pragma unroll
        for (int qt = 0; qt < 4; qt++) accO[dt][qt] = zf;
    #pragma unroll
    for (int qt = 0; qt < 4; qt++) { m_st[qt] = -1e30f; l_st[qt] = 0.f; }

    // staging geometry: 4 waves x 2 column-groups cover c=0..7 (8 rows each)
    int rowL = lane >> 3;
    int sgl = ((lane & 7) ^ ((lane >> 3) & 7)) * 8;   // swizzled global seg (shorts)
    const __hip_bfloat16* kg0 = k + ((size_t)bh * SEQ) * HS;
    const __hip_bfloat16* vtg0 = v + (size_t)bh * HS * SEQ;   // v pre-transposed (bh,e,s)
    short* myP = &sP[w][0];

    // prologue: stage K-tile 0 into buffer 0
    #pragma unroll
    for (int i = 0; i < 2; i++) {
        int c = w * 2 + i;
        int rr = c * 8 + rowL;
        gld16(kg0  + (size_t)rr * HS  + sgl, (char*)&sK[0][0]  + c * 1024);
        gld16(vtg0 + (size_t)rr * SEQ + sgl, (char*)&sVT[0][0] + c * 1024);
    }
    __syncthreads();

    int buf = 0;
    for (int kc = 0; kc < 16; kc++) {
        // prefetch next K-tile into the other buffer (in flight during compute)
        if (kc < 15) {
            const __hip_bfloat16* kg  = kg0  + (size_t)(kc + 1) * 64 * HS;
            const __hip_bfloat16* vtg = vtg0 + (kc + 1) * 64;
            #pragma unroll
            for (int i = 0; i < 2; i++) {
                int c = w * 2 + i;
                int rr = c * 8 + rowL;
                gld16(kg  + (size_t)rr * HS  + sgl, (char*)&sK[buf ^ 1][0]  + c * 1024);
                gld16(vtg + (size_t)rr * SEQ + sgl, (char*)&sVT[buf ^ 1][0] + c * 1024);
            }
        }
        short* cK  = &sK[buf][0];
        short* cVT = &sVT[buf][0];

        // all sK/sVT reads up front
        bf16x8 vf[4][2];
        #pragma unroll
        for (int dt = 0; dt < 4; dt++)
            #pragma unroll
            for (int s = 0; s < 2; s++)
                vf[dt][s] = *(bf16x8*)&cVT[(dt * 16 + l16) * 64 + (((s * 4 + quad) ^ (l16 & 7)) * 8)];
        f32x4 sc[4][4];   // [kt][qt]
        #pragma unroll
        for (int kt = 0; kt < 4; kt++) {
            bf16x8 kf0 = *(bf16x8*)&cK[(kt * 16 + l16) * 64 + ((quad ^ (l16 & 7)) * 8)];
            bf16x8 kf1 = *(bf16x8*)&cK[(kt * 16 + l16) * 64 + (((4 + quad) ^ (l16 & 7)) * 8)];
            #pragma unroll
            for (int qt = 0; qt < 4; qt++) {
                f32x4 c = __builtin_amdgcn_mfma_f32_16x16x32_bf16(kf0, qf[qt][0], zf, 0, 0, 0);
                sc[kt][qt] = __builtin_amdgcn_mfma_f32_16x16x32_bf16(kf1, qf[qt][1], c, 0, 0, 0);
            }
        }
        // scale + mask (mask indexed by key row)
        #pragma unroll
        for (int kt = 0; kt < 4; kt++) {
            f32x4 mk = *(f32x4*)&mskf[kc * 64 + kt * 16 + quad * 4];
            #pragma unroll
            for (int qt = 0; qt < 4; qt++)
                #pragma unroll
                for (int r = 0; r < 4; r++)
                    sc[kt][qt][r] = sc[kt][qt][r] * scale + mk[r];
        }
        // online softmax per query column
        #pragma unroll
        for (int qt = 0; qt < 4; qt++) {
            float rm = -1e30f;
            #pragma unroll
            for (int kt = 0; kt < 4; kt++)
                #pragma unroll
                for (int r = 0; r < 4; r++) rm = fmaxf(rm, sc[kt][qt][r]);
            rm = fmaxf(rm, __shfl_xor(rm, 16));
            rm = fmaxf(rm, __shfl_xor(rm, 32));
            float mnew = fmaxf(m_st[qt], rm);
            float corr = __expf(m_st[qt] - mnew);
            m_st[qt] = mnew;
            float ps = 0.f;
            #pragma unroll
            for (int kt = 0; kt < 4; kt++) {
                union { uint2 u; short s[4]; } pk;
                #pragma unroll
                for (int r = 0; r < 4; r++) {
                    float p = __expf(sc[kt][qt][r] - mnew);
                    ps += p;
                    pk.s[r] = f2bf_s(p);
                }
                *(uint2*)&myP[(qt * 16 + l16) * 64 +
                              (((kt * 2 + (quad >> 1)) ^ (l16 & 7)) * 8) + (quad & 1) * 4] = pk.u;
            }
            ps += __shfl_xor(ps, 16);
            ps += __shfl_xor(ps, 32);
            l_st[qt] = l_st[qt] * corr + ps;
            #pragma unroll
            for (int dt = 0; dt < 4; dt++) accO[dt][qt] *= corr;
        }
        asm volatile("" ::: "memory");   // keep pf reads after P writes (same-wave DS is in-order)
        // PV: O^T += V^T @ P^T
        #pragma unroll
        for (int qt = 0; qt < 4; qt++) {
            bf16x8 pf0 = *(bf16x8*)&myP[(qt * 16 + l16) * 64 + ((quad ^ (l16 & 7)) * 8)];
            bf16x8 pf1 = *(bf16x8*)&myP[(qt * 16 + l16) * 64 + (((4 + quad) ^ (l16 & 7)) * 8)];
            #pragma unroll
            for (int dt = 0; dt < 4; dt++) {
                accO[dt][qt] = __builtin_amdgcn_mfma_f32_16x16x32_bf16(vf[dt][0], pf0, accO[dt][qt], 0, 0, 0);
                accO[dt][qt] = __builtin_amdgcn_mfma_f32_16x16x32_bf16(vf[dt][1], pf1, accO[dt][qt], 0, 0, 0);
            }
        }
        __syncthreads();   // drains prefetch (full compute phase to land); next buffer ready
        buf ^= 1;
    }

    // epilogue: O = O^T / l, pack 4 consecutive dims per b64 store
    #pragma unroll
    for (int qt = 0; qt < 4; qt++) {
        float inv = 1.f / l_st[qt];
        int row = qb0 + qt * 16 + l16;
        __hip_bfloat16* orow = ao + ((size_t)(b * SEQ + row)) * D_MODEL + hh * HS;
        #pragma unroll
        for (int dt = 0; dt < 4; dt++) {
            union { uint2 u; short s[4]; } pk;
            #pragma unroll
            for (int r = 0; r < 4; r++) pk.s[r] = f2bf_s(accO[dt][qt][r] * inv);
            *(uint2*)(orow + dt * 16 + quad * 4) = pk.u;
        }
    }
}

// ---------------------------------------------------------------- head FC1: (8,768)@(768,3072)+relu
__global__ __launch_bounds__(256) void fc1_kernel(
    const float* __restrict__ A, const float* __restrict__ W,
    const float* __restrict__ bias, float* __restrict__ out)
{
    __shared__ float sa[D_MODEL];
    int row = blockIdx.x, t = threadIdx.x;
    for (int i = t; i < D_MODEL; i += 256) sa[i] = A[(size_t)row * D_MODEL + i];
    __syncthreads();
    int col = blockIdx.y * 256 + t;
    float s = 0.f;
    #pragma unroll 8
    for (int kk = 0; kk < D_MODEL; kk++) s = fmaf(sa[kk], W[(size_t)kk * DFF + col], s);
    s += bias[col];
    out[(size_t)row * DFF + col] = fmaxf(s, 0.f);
}

// ---------------------------------------------------------------- head FC2: (8,3072)@(3072,16)
__global__ __launch_bounds__(256) void fc2_kernel(
    const float* __restrict__ A, const float* __restrict__ W,
    const float* __restrict__ bias, float* __restrict__ out)
{
    __shared__ float wred[4][NCLS];
    int row = blockIdx.x, t = threadIdx.x;
    int wave = t >> 6, lane = t & 63;
    const float* a = A + (size_t)row * DFF;
    float acc[NCLS];
    #pragma unroll
    for (int c = 0; c < NCLS; c++) acc[c] = 0.f;
    for (int kk = t; kk < DFF; kk += 256) {
        float av = a[kk];
        const float4* wr = (const float4*)(W + (size_t)kk * NCLS);
        float4 w0 = wr[0], w1 = wr[1], w2 = wr[2], w3 = wr[3];
        acc[0]  = fmaf(av, w0.x, acc[0]);  acc[1]  = fmaf(av, w0.y, acc[1]);
        acc[2]  = fmaf(av, w0.z, acc[2]);  acc[3]  = fmaf(av, w0.w, acc[3]);
        acc[4]  = fmaf(av, w1.x, acc[4]);  acc[5]  = fmaf(av, w1.y, acc[5]);
        acc[6]  = fmaf(av, w1.z, acc[6]);  acc[7]  = fmaf(av, w1.w, acc[7]);
        acc[8]  = fmaf(av, w2.x, acc[8]);  acc[9]  = fmaf(av, w2.y, acc[9]);
        acc[10] = fmaf(av, w2.z, acc[10]); acc[11] = fmaf(av, w2.w, acc[11]);
        acc[12] = fmaf(av, w3.x, acc[12]); acc[13] = fmaf(av, w3.y, acc[13]);
        acc[14] = fmaf(av, w3.z, acc[14]); acc[15] = fmaf(av, w3.w, acc[15]);
    }
    #pragma unroll
    for (int c = 0; c < NCLS; c++)
        #pragma unroll
        for (int off = 32; off; off >>= 1) acc[c] += __shfl_down(acc[c], off);
    if (lane == 0)
        #pragma unroll
        for (int c = 0; c < NCLS; c++) wred[wave][c] = acc[c];
    __syncthreads();
    if (t < NCLS)
        out[row * NCLS + t] = wred[0][t] + wred[1][t] + wred[2][t] + wred[3][t] + bias[t];
}

// ---------------------------------------------------------------- launch
extern "C" void kernel_launch(void* const* d_in, const int* in_sizes, int n_in,
                              void* d_out, int out_size, void* d_ws, size_t ws_size,
                              hipStream_t stream)
{
    const int*   x     = (const int*)  d_in[0];
    const int*   amask = (const int*)  d_in[1];
    const float* tok   = (const float*)d_in[2];
    const float* pos   = (const float*)d_in[3];
    const float* Wq    = (const float*)d_in[4];
    const float* Wk    = (const float*)d_in[5];
    const float* Wv    = (const float*)d_in[6];
    const float* Wo    = (const float*)d_in[7];
    const float* bo    = (const float*)d_in[8];
    const float* ln1w  = (const float*)d_in[9];
    const float* ln1b  = (const float*)d_in[10];
    const float* ln2w  = (const float*)d_in[11];
    const float* ln2b  = (const float*)d_in[12];
    const float* W1    = (const float*)d_in[13];
    const float* b1    = (const float*)d_in[14];
    const float* W2    = (const float*)d_in[15];
    const float* b2    = (const float*)d_in[16];
    const float* lnfw  = (const float*)d_in[17];
    const float* lnfb  = (const float*)d_in[18];
    const float* cW1   = (const float*)d_in[19];
    const float* cb1   = (const float*)d_in[20];
    const float* cW2   = (const float*)d_in[21];
    const float* cb2   = (const float*)d_in[22];

    char* base = (char*)d_ws;
    const size_t MD = (size_t)MROWS * D_MODEL;
    float* h = (float*)base;                         base += MD * 4;
    __hip_bfloat16* xn = (__hip_bfloat16*)base;      base += MD * 2;
    __hip_bfloat16* qb = (__hip_bfloat16*)base;      base += MD * 2;
    __hip_bfloat16* kb = (__hip_bfloat16*)base;      base += MD * 2;
    __hip_bfloat16* vb = (__hip_bfloat16*)base;      base += MD * 2;   // holds V^T (bh,e,s)
    __hip_bfloat16* vT = (__hip_bfloat16*)base;      base += MD * 2;   // unused (kept for layout)
    __hip_bfloat16* ff = (__hip_bfloat16*)base;      base += (size_t)MROWS * DFF * 2;
    float* lnf = (float*)base;                       base += (size_t)NB * D_MODEL * 4;
    float* cls = (float*)base;                       base += (size_t)NB * DFF * 4;
    __hip_bfloat16* wQKV = (__hip_bfloat16*)base;    base += (size_t)NLAYER * 3 * D_MODEL * D_MODEL * 2;
    __hip_bfloat16* wTo = (__hip_bfloat16*)base;     base += (size_t)NLAYER * D_MODEL * D_MODEL * 2;
    __hip_bfloat16* wT1 = (__hip_bfloat16*)base;     base += (size_t)NLAYER * D_MODEL * DFF * 2;
    __hip_bfloat16* wT2 = (__hip_bfloat16*)base;     base += (size_t)NLAYER * DFF * D_MODEL * 2;
    (void)vT;

    const size_t SQW = (size_t)D_MODEL * D_MODEL;
    const size_t SFF = (size_t)D_MODEL * DFF;

    convw_kernel<1><<<dim3(12,12,4), 256, 0, stream>>>(Wq, wQKV + 0 * SQW, D_MODEL, D_MODEL, SQW, 3 * SQW);
    convw_kernel<1><<<dim3(12,12,4), 256, 0, stream>>>(Wk, wQKV + 1 * SQW, D_MODEL, D_MODEL, SQW, 3 * SQW);
    convw_kernel<1><<<dim3(12,12,4), 256, 0, stream>>>(Wv, wQKV + 2 * SQW, D_MODEL, D_MODEL, SQW, 3 * SQW);
    convw_kernel<0><<<dim3(12,12,4), 256, 0, stream>>>(Wo, wTo, D_MODEL, D_MODEL, SQW, SQW);
    convw_kernel<0><<<dim3(12,48,4), 256, 0, stream>>>(W1, wT1, D_MODEL, DFF, SFF, SFF);
    convw_kernel<0><<<dim3(48,12,4), 256, 0, stream>>>(W2, wT2, DFF, D_MODEL, SFF, SFF);

    embed_kernel<<<MROWS / 4, 256, 0, stream>>>(x, tok, pos, h);

    dim3 gQKV(MROWS / 128, (3 * D_MODEL) / 128);
    dim3 gDS(MROWS / 128, D_MODEL / 128, 2);   // split-K=2
    dim3 gF(MROWS / 128, DFF / 128);
    for (int l = 0; l < NLAYER; l++) {
        ln_kernel<1><<<MROWS / 4, 256, 0, stream>>>(h, ln1w + l * D_MODEL, ln1b + l * D_MODEL, xn, 1, 0);
        gemm128<1><<<gQKV, 512, 0, stream>>>(xn, wQKV + l * 3 * SQW, nullptr, nullptr, qb, MROWS, 3 * D_MODEL, D_MODEL, 0);
        attn_mfma_kernel<<<NB * NHEAD * 4, 256, 0, stream>>>(qb, kb, vb, amask, xn);
        gemm128<3><<<gDS, 512, 0, stream>>>(xn, wTo + l * SQW, bo + l * D_MODEL, nullptr, h, MROWS, D_MODEL, D_MODEL, 0);
        ln_kernel<1><<<MROWS / 4, 256, 0, stream>>>(h, ln2w + l * D_MODEL, ln2b + l * D_MODEL, xn, 1, 0);
        gemm128<2><<<gF, 512, 0, stream>>>(xn, wT1 + l * SFF, b1 + l * DFF, nullptr, ff, MROWS, DFF, D_MODEL, 1);
        gemm128<3><<<gDS, 512, 0, stream>>>(ff, wT2 + l * SFF, b2 + l * D_MODEL, nullptr, h, MROWS, D_MODEL, DFF, 0);
    }
    ln_kernel<0><<<NB / 4, 256, 0, stream>>>(h, lnfw, lnfb, lnf, SEQ, SEQ - 1);
    fc1_kernel<<<dim3(NB, DFF / 256), 256, 0, stream>>>(lnf, cW1, cb1, cls);
    fc2_kernel<<<NB, 256, 0, stream>>>(cls, cW2, cb2, (float*)d_out);
}

// Round 10
// 1538.182 us; speedup vs baseline: 1.0413x; 1.0413x over previous
//
#include <hip/hip_runtime.h>
#include <hip/hip_bf16.h>

#define D_MODEL 768
#define SEQ     1024
#define NB      8
#define NHEAD   12
#define HS      64
#define NLAYER  4
#define DFF     3072
#define NCLS    16
#define MROWS   (NB*SEQ)   // 8192

typedef float f32x4  __attribute__((ext_vector_type(4)));
typedef short bf16x8 __attribute__((ext_vector_type(8)));

__device__ __forceinline__ short f2bf_s(float x) {
    __hip_bfloat16 h = __float2bfloat16(x);
    union { __hip_bfloat16 h; short s; } u; u.h = h; return u.s;
}

// async global->LDS, 16B per lane; lds base must be wave-uniform (HW adds lane*16)
__device__ __forceinline__ void gld16(const void* g, void* l) {
    __builtin_amdgcn_global_load_lds((const __attribute__((address_space(1))) void*)g,
                                     (__attribute__((address_space(3))) void*)l, 16, 0, 0);
}

// ---------------------------------------------------------------- embedding
// one row per WAVE: 12 f32/lane via float4, no LDS/barriers. grid = MROWS/4.
__global__ __launch_bounds__(256) void embed_kernel(
    const int* __restrict__ x, const float* __restrict__ tok,
    const float* __restrict__ pos, float* __restrict__ h)
{
    int wave = threadIdx.x >> 6, lane = threadIdx.x & 63;
    int row = blockIdx.x * 4 + wave;
    int s   = row & (SEQ - 1);
    int id  = x[row];
    const float4* te = (const float4*)(tok + (size_t)id * D_MODEL);
    const float4* pe = (const float4*)(pos + (size_t)s  * D_MODEL);
    float4* hr = (float4*)(h + (size_t)row * D_MODEL);
    #pragma unroll
    for (int j = 0; j < 3; j++) {
        float4 a = te[j * 64 + lane], p = pe[j * 64 + lane];
        a.x += p.x; a.y += p.y; a.z += p.z; a.w += p.w;
        hr[j * 64 + lane] = a;
    }
}

// ---------------------------------------------------------------- layernorm
// one row per WAVE (4 rows/block): float4 loads, full-wave shfl_xor reduce,
// ZERO LDS / barriers. grid = rows/4.
template<int BF16OUT>
__global__ __launch_bounds__(256) void ln_kernel(
    const float* __restrict__ in, const float* __restrict__ w,
    const float* __restrict__ b, void* __restrict__ outv,
    int row_stride, int row_offset)
{
    int wave = threadIdx.x >> 6, lane = threadIdx.x & 63;
    int r = blockIdx.x * 4 + wave;
    const float4* xr = (const float4*)(in + (size_t)(r * row_stride + row_offset) * D_MODEL);
    float4 v0 = xr[lane], v1 = xr[64 + lane], v2 = xr[128 + lane];
    float s = v0.x + v0.y + v0.z + v0.w
            + v1.x + v1.y + v1.z + v1.w
            + v2.x + v2.y + v2.z + v2.w;
    #pragma unroll
    for (int off = 32; off; off >>= 1) s += __shfl_xor(s, off);
    float mu = s * (1.f / D_MODEL);
    float4 d0, d1, d2;
    d0.x = v0.x - mu; d0.y = v0.y - mu; d0.z = v0.z - mu; d0.w = v0.w - mu;
    d1.x = v1.x - mu; d1.y = v1.y - mu; d1.z = v1.z - mu; d1.w = v1.w - mu;
    d2.x = v2.x - mu; d2.y = v2.y - mu; d2.z = v2.z - mu; d2.w = v2.w - mu;
    float q = d0.x*d0.x + d0.y*d0.y + d0.z*d0.z + d0.w*d0.w
            + d1.x*d1.x + d1.y*d1.y + d1.z*d1.z + d1.w*d1.w
            + d2.x*d2.x + d2.y*d2.y + d2.z*d2.z + d2.w*d2.w;
    #pragma unroll
    for (int off = 32; off; off >>= 1) q += __shfl_xor(q, off);
    float rstd = rsqrtf(q * (1.f / D_MODEL) + 1e-5f);
    const float4* w4 = (const float4*)w;
    const float4* b4 = (const float4*)b;
    float4 dd[3] = {d0, d1, d2};
    if (BF16OUT) {
        short* yr = (short*)outv + (size_t)r * D_MODEL;
        #pragma unroll
        for (int j = 0; j < 3; j++) {
            float4 ww = w4[j * 64 + lane], bb = b4[j * 64 + lane];
            union { uint2 u; short s[4]; } pk;
            pk.s[0] = f2bf_s(dd[j].x * rstd * ww.x + bb.x);
            pk.s[1] = f2bf_s(dd[j].y * rstd * ww.y + bb.y);
            pk.s[2] = f2bf_s(dd[j].z * rstd * ww.z + bb.z);
            pk.s[3] = f2bf_s(dd[j].w * rstd * ww.w + bb.w);
            *(uint2*)(yr + j * 256 + lane * 4) = pk.u;
        }
    } else {
        float4* yr = (float4*)((float*)outv + (size_t)r * D_MODEL);
        #pragma unroll
        for (int j = 0; j < 3; j++) {
            float4 ww = w4[j * 64 + lane], bb = b4[j * 64 + lane];
            float4 y;
            y.x = dd[j].x * rstd * ww.x + bb.x;
            y.y = dd[j].y * rstd * ww.y + bb.y;
            y.z = dd[j].z * rstd * ww.z + bb.z;
            y.w = dd[j].w * rstd * ww.w + bb.w;
            yr[j * 64 + lane] = y;
        }
    }
}

// --------------------------------------------- weight convert+transpose to bf16
template<int MODE>
__global__ __launch_bounds__(256) void convw_kernel(
    const float* __restrict__ W, __hip_bfloat16* __restrict__ BT,
    int K, int N, size_t in_stride, size_t out_stride)
{
    __shared__ __hip_bfloat16 sT[64][72];
    W  += (size_t)blockIdx.z * in_stride;
    BT += (size_t)blockIdx.z * out_stride;
    int k0 = blockIdx.x * 64, n0 = blockIdx.y * 64;
    int t = threadIdx.x;
    int kl = t >> 4, nl4 = (t & 15) * 4;
    #pragma unroll
    for (int i = 0; i < 4; i++) {
        int k = k0 + kl + i * 16;
        int n = n0 + nl4;
        const float* src = (MODE == 0) ? (W + (size_t)k * N + n)
                                       : (W + ((size_t)(n >> 6) * K + k) * 64 + (n & 63));
        float4 v = *(const float4*)src;
        sT[nl4 + 0][kl + i*16] = __float2bfloat16(v.x);
        sT[nl4 + 1][kl + i*16] = __float2bfloat16(v.y);
        sT[nl4 + 2][kl + i*16] = __float2bfloat16(v.z);
        sT[nl4 + 3][kl + i*16] = __float2bfloat16(v.w);
    }
    __syncthreads();
    int nl = t >> 2, seg = (t & 3) * 16;
    uint4* dst = (uint4*)(BT + (size_t)(n0 + nl) * K + k0 + seg);
    dst[0] = *(uint4*)&sT[nl][seg];
    dst[1] = *(uint4*)&sT[nl][seg + 8];
}

// ---------------------------------------------------------------- bf16 MFMA GEMM
// R8-proven (measured best): 128x128 tile, 8 waves (2M x 4N), 3 LDS buffers,
// 2-deep prefetch, counted vmcnt(2), ONE s_barrier per K-step, compiler-managed
// lgkm waits. 3 blocks/CU x 8 waves = 6 waves/SIMD.
// OMODE: 0 = f32 out (+bias,+res)   1 = QKV scatter (V third written TRANSPOSED
//        to (bh,e,s) with packed uint2 stores)   2 = bf16 out
//        3 = split-K over blockIdx.z, atomicAdd f32 into C
template<int OMODE>
__global__ __launch_bounds__(512, 6) void gemm128(
    const __hip_bfloat16* __restrict__ A, const __hip_bfloat16* __restrict__ BT,
    const float* __restrict__ bias, const float* __restrict__ res,
    void* __restrict__ Cv, int M, int N, int K, int relu)
{
    __shared__ short sA[3][128 * 32];
    __shared__ short sB[3][128 * 32];
    int t = threadIdx.x;
    int wave = t >> 6, lane = t & 63;
    int l16 = lane & 15, quad = (lane >> 4) & 3;
    int wm = wave >> 2, wn = wave & 3;          // 2M x 4N wave grid
    int bm = blockIdx.x * 128, bn = blockIdx.y * 128;

    int kbeg = 0, kend = K;
    if (OMODE == 3) { int KS = K >> 1; kbeg = blockIdx.z * KS; kend = kbeg + KS; }
    int nsteps = (kend - kbeg) >> 5;

    int u = lane >> 2;
    int skey = ((u & 3) ^ ((u >> 2) & 3));
    int sseg = (lane & 3) ^ skey;
    int fkey = ((l16 & 3) ^ ((l16 >> 2) & 3));

    const f32x4 zf = {0.f, 0.f, 0.f, 0.f};
    f32x4 acc[4][2];
    #pragma unroll
    for (int mi = 0; mi < 4; mi++)
        #pragma unroll
        for (int ni = 0; ni < 2; ni++) acc[mi][ni] = zf;

    // each wave stages chunk 'wave' (16 rows) of A and of B
    const __hip_bfloat16* pA = A  + (size_t)(bm + (wave << 4) + u) * K + kbeg + sseg * 8;
    const __hip_bfloat16* pB = BT + (size_t)(bn + (wave << 4) + u) * K + kbeg + sseg * 8;

    #define STAGE(bufi, kk) do { \
        gld16(pA + (kk), &sA[bufi][wave * 512]); \
        gld16(pB + (kk), &sB[bufi][wave * 512]); \
    } while (0)

    STAGE(0, 0);
    if (nsteps > 1) STAGE(1, 32);

    int bufr = 0, bufs = 2;
    for (int it = 0; it < nsteps; ++it) {
        // wait own loads for tile 'it' (tile it+1's 2 ops stay in flight)
        if (it + 1 < nsteps) { asm volatile("s_waitcnt vmcnt(2)" ::: "memory"); }
        else                 { asm volatile("s_waitcnt vmcnt(0)" ::: "memory"); }
        __builtin_amdgcn_sched_barrier(0);
        __builtin_amdgcn_s_barrier();
        __builtin_amdgcn_sched_barrier(0);

        const short* curA = &sA[bufr][0];
        const short* curB = &sB[bufr][0];
        bf16x8 aF[4], bF[2];
        #pragma unroll
        for (int mi = 0; mi < 4; mi++)
            aF[mi] = *(const bf16x8*)&curA[(wm * 64 + mi * 16 + l16) * 32 + ((quad ^ fkey) * 8)];
        #pragma unroll
        for (int ni = 0; ni < 2; ni++)
            bF[ni] = *(const bf16x8*)&curB[(wn * 32 + ni * 16 + l16) * 32 + ((quad ^ fkey) * 8)];

        if (it + 2 < nsteps) STAGE(bufs, (it + 2) * 32);   // 2-ahead prefetch

        // compiler-managed counted lgkm waits; all frags consumed below, so this
        // wave's ds_reads complete before it reaches the next barrier (WAR ok).
        #pragma unroll
        for (int ni = 0; ni < 2; ni++)
            #pragma unroll
            for (int mi = 0; mi < 4; mi++)
                acc[mi][ni] = __builtin_amdgcn_mfma_f32_16x16x32_bf16(aF[mi], bF[ni], acc[mi][ni], 0, 0, 0);

        bufr = (bufr == 2) ? 0 : bufr + 1;
        bufs = (bufs == 2) ? 0 : bufs + 1;
    }
    #undef STAGE

    #pragma unroll
    for (int mi = 0; mi < 4; mi++) {
        #pragma unroll
        for (int ni = 0; ni < 2; ni++) {
            int row0 = bm + wm * 64 + mi * 16 + quad * 4;
            int col  = bn + wn * 32 + ni * 16 + l16;
            if (OMODE == 1) {
                // QKV scatter. row0 % 4 == 0, rows row0..row0+3 share bb.
                int which = col / D_MODEL, cc = col % D_MODEL;
                int hh = cc >> 6, e = cc & 63;
                int bb = row0 >> 10, ss0 = row0 & 1023;
                union { uint2 u; short s[4]; } pk;
                #pragma unroll
                for (int r = 0; r < 4; r++) pk.s[r] = f2bf_s(acc[mi][ni][r]);
                __hip_bfloat16* dstb = (__hip_bfloat16*)Cv + (size_t)which * MROWS * D_MODEL;
                if (which == 2) {
                    // V -> (bh, e, s) transposed; 4 consecutive s -> one uint2
                    *(uint2*)(dstb + ((size_t)(bb * NHEAD + hh)) * HS * SEQ + (size_t)e * SEQ + ss0) = pk.u;
                } else {
                    short* p = (short*)(dstb + (((size_t)(bb * NHEAD + hh)) * SEQ + ss0) * HS + e);
                    #pragma unroll
                    for (int r = 0; r < 4; r++) p[r * HS] = pk.s[r];
                }
                continue;
            }
            #pragma unroll
            for (int r = 0; r < 4; r++) {
                int row = row0 + r;
                float v = acc[mi][ni][r];
                if (OMODE == 3) {
                    float* C = (float*)Cv;
                    if (blockIdx.z == 0 && bias) v += bias[col];
                    unsafeAtomicAdd(&C[(size_t)row * N + col], v);
                    continue;
                }
                if (bias) v += bias[col];
                if (relu) v = fmaxf(v, 0.f);
                if (OMODE == 0) {
                    float* C = (float*)Cv;
                    if (res) v += res[(size_t)row * N + col];
                    C[(size_t)row * N + col] = v;
                } else {
                    ((__hip_bfloat16*)Cv)[(size_t)row * N + col] = __float2bfloat16(v);
                }
            }
        }
    }
    (void)M;
}

// ---------------------------------------------------------------- MFMA flash attention (S^T orientation)
// Block = 4 waves = 256 queries of one (b,h); wave owns 64 queries (4 qt-tiles).
// K/VT staging shared by all 4 waves. XCD-bijective remap (K/VT L2-local).
// R10: T5 s_setprio(1) around MFMA clusters — measured +4-7% on attn-class
// kernels (independent phase-skewed blocks), null on lockstep GEMMs.
__global__ __launch_bounds__(256, 2) void attn_mfma_kernel(
    const __hip_bfloat16* __restrict__ q, const __hip_bfloat16* __restrict__ k,
    const __hip_bfloat16* __restrict__ v, const int* __restrict__ mask,
    __hip_bfloat16* __restrict__ ao)
{
    __shared__ short sK[2][64 * 64];
    __shared__ short sVT[2][64 * 64];
    __shared__ short sP[4][64 * 64];
    __shared__ float mskf[SEQ];
    int bid = blockIdx.x;                 // 384 = 8 XCD x 48
    int xcd = bid & 7, j = bid >> 3;      // j in 0..47
    int bh  = ((j >> 2) << 3) | xcd;      // bijective: bh in 0..95
    int qt4 = j & 3;
    int b = bh / NHEAD, hh = bh % NHEAD;
    int t = threadIdx.x, w = t >> 6, lane = t & 63;
    int l16 = lane & 15, quad = lane >> 4;
    const float scale = 0.036084391824351615f;  // 768^-0.5
    const f32x4 zf = {0.f, 0.f, 0.f, 0.f};

    #pragma unroll
    for (int i = 0; i < 4; i++) {
        int idx = t + i * 256;
        mskf[idx] = mask[b * SEQ + idx] ? 0.f : -1e30f;
    }

    // Q B-frags: lane n=query(l16), k=dim s*32+quad*8..+7
    int qb0 = qt4 * 256 + w * 64;
    const __hip_bfloat16* qbase = q + ((size_t)bh * SEQ + qb0) * HS;
    bf16x8 qf[4][2];
    #pragma unroll
    for (int qt = 0; qt < 4; qt++)
        #pragma unroll
        for (int s = 0; s < 2; s++)
            qf[qt][s] = *(const bf16x8*)(qbase + (qt * 16 + l16) * HS + s * 32 + quad * 8);

    f32x4 accO[4][4];            // [dt][qt]: O^T tile, row=dim dt*16+quad*4+r, col=query qt*16+l16
    float m_st[4], l_st[4];
    #pragma unroll
    for (int dt = 0; dt < 4; dt++)
        #pragma unroll
        for (int qt = 0; qt < 4; qt++) accO[dt][qt] = zf;
    #pragma unroll
    for (int qt = 0; qt < 4; qt++) { m_st[qt] = -1e30f; l_st[qt] = 0.f; }

    // staging geometry: 4 waves x 2 column-groups cover c=0..7 (8 rows each)
    int rowL = lane >> 3;
    int sgl = ((lane & 7) ^ ((lane >> 3) & 7)) * 8;   // swizzled global seg (shorts)
    const __hip_bfloat16* kg0 = k + ((size_t)bh * SEQ) * HS;
    const __hip_bfloat16* vtg0 = v + (size_t)bh * HS * SEQ;   // v pre-transposed (bh,e,s)
    short* myP = &sP[w][0];

    // prologue: stage K-tile 0 into buffer 0
    #pragma unroll
    for (int i = 0; i < 2; i++) {
        int c = w * 2 + i;
        int rr = c * 8 + rowL;
        gld16(kg0  + (size_t)rr * HS  + sgl, (char*)&sK[0][0]  + c * 1024);
        gld16(vtg0 + (size_t)rr * SEQ + sgl, (char*)&sVT[0][0] + c * 1024);
    }
    __syncthreads();

    int buf = 0;
    for (int kc = 0; kc < 16; kc++) {
        // prefetch next K-tile into the other buffer (in flight during compute)
        if (kc < 15) {
            const __hip_bfloat16* kg  = kg0  + (size_t)(kc + 1) * 64 * HS;
            const __hip_bfloat16* vtg = vtg0 + (kc + 1) * 64;
            #pragma unroll
            for (int i = 0; i < 2; i++) {
                int c = w * 2 + i;
                int rr = c * 8 + rowL;
                gld16(kg  + (size_t)rr * HS  + sgl, (char*)&sK[buf ^ 1][0]  + c * 1024);
                gld16(vtg + (size_t)rr * SEQ + sgl, (char*)&sVT[buf ^ 1][0] + c * 1024);
            }
        }
        short* cK  = &sK[buf][0];
        short* cVT = &sVT[buf][0];

        // all sK/sVT reads up front
        bf16x8 vf[4][2];
        #pragma unroll
        for (int dt = 0; dt < 4; dt++)
            #pragma unroll
            for (int s = 0; s < 2; s++)
                vf[dt][s] = *(bf16x8*)&cVT[(dt * 16 + l16) * 64 + (((s * 4 + quad) ^ (l16 & 7)) * 8)];
        f32x4 sc[4][4];   // [kt][qt]
        __builtin_amdgcn_s_setprio(1);
        #pragma unroll
        for (int kt = 0; kt < 4; kt++) {
            bf16x8 kf0 = *(bf16x8*)&cK[(kt * 16 + l16) * 64 + ((quad ^ (l16 & 7)) * 8)];
            bf16x8 kf1 = *(bf16x8*)&cK[(kt * 16 + l16) * 64 + (((4 + quad) ^ (l16 & 7)) * 8)];
            #pragma unroll
            for (int qt = 0; qt < 4; qt++) {
                f32x4 c = __builtin_amdgcn_mfma_f32_16x16x32_bf16(kf0, qf[qt][0], zf, 0, 0, 0);
                sc[kt][qt] = __builtin_amdgcn_mfma_f32_16x16x32_bf16(kf1, qf[qt][1], c, 0, 0, 0);
            }
        }
        __builtin_amdgcn_s_setprio(0);
        // scale + mask (mask indexed by key row)
        #pragma unroll
        for (int kt = 0; kt < 4; kt++) {
            f32x4 mk = *(f32x4*)&mskf[kc * 64 + kt * 16 + quad * 4];
            #pragma unroll
            for (int qt = 0; qt < 4; qt++)
                #pragma unroll
                for (int r = 0; r < 4; r++)
                    sc[kt][qt][r] = sc[kt][qt][r] * scale + mk[r];
        }
        // online softmax per query column
        #pragma unroll
        for (int qt = 0; qt < 4; qt++) {
            float rm = -1e30f;
            #pragma unroll
            for (int kt = 0; kt < 4; kt++)
                #pragma unroll
                for (int r = 0; r < 4; r++) rm = fmaxf(rm, sc[kt][qt][r]);
            rm = fmaxf(rm, __shfl_xor(rm, 16));
            rm = fmaxf(rm, __shfl_xor(rm, 32));
            float mnew = fmaxf(m_st[qt], rm);
            float corr = __expf(m_st[qt] - mnew);
            m_st[qt] = mnew;
            float ps = 0.f;
            #pragma unroll
            for (int kt = 0; kt < 4; kt++) {
                union { uint2 u; short s[4]; } pk;
                #pragma unroll
                for (int r = 0; r < 4; r++) {
                    float p = __expf(sc[kt][qt][r] - mnew);
                    ps += p;
                    pk.s[r] = f2bf_s(p);
                }
                *(uint2*)&myP[(qt * 16 + l16) * 64 +
                              (((kt * 2 + (quad >> 1)) ^ (l16 & 7)) * 8) + (quad & 1) * 4] = pk.u;
            }
            ps += __shfl_xor(ps, 16);
            ps += __shfl_xor(ps, 32);
            l_st[qt] = l_st[qt] * corr + ps;
            #pragma unroll
            for (int dt = 0; dt < 4; dt++) accO[dt][qt] *= corr;
        }
        asm volatile("" ::: "memory");   // keep pf reads after P writes (same-wave DS is in-order)
        // PV: O^T += V^T @ P^T
        __builtin_amdgcn_s_setprio(1);
        #pragma unroll
        for (int qt = 0; qt < 4; qt++) {
            bf16x8 pf0 = *(bf16x8*)&myP[(qt * 16 + l16) * 64 + ((quad ^ (l16 & 7)) * 8)];
            bf16x8 pf1 = *(bf16x8*)&myP[(qt * 16 + l16) * 64 + (((4 + quad) ^ (l16 & 7)) * 8)];
            #pragma unroll
            for (int dt = 0; dt < 4; dt++) {
                accO[dt][qt] = __builtin_amdgcn_mfma_f32_16x16x32_bf16(vf[dt][0], pf0, accO[dt][qt], 0, 0, 0);
                accO[dt][qt] = __builtin_amdgcn_mfma_f32_16x16x32_bf16(vf[dt][1], pf1, accO[dt][qt], 0, 0, 0);
            }
        }
        __builtin_amdgcn_s_setprio(0);
        __syncthreads();   // drains prefetch (full compute phase to land); next buffer ready
        buf ^= 1;
    }

    // epilogue: O = O^T / l, pack 4 consecutive dims per b64 store
    #pragma unroll
    for (int qt = 0; qt < 4; qt++) {
        float inv = 1.f / l_st[qt];
        int row = qb0 + qt * 16 + l16;
        __hip_bfloat16* orow = ao + ((size_t)(b * SEQ + row)) * D_MODEL + hh * HS;
        #pragma unroll
        for (int dt = 0; dt < 4; dt++) {
            union { uint2 u; short s[4]; } pk;
            #pragma unroll
            for (int r = 0; r < 4; r++) pk.s[r] = f2bf_s(accO[dt][qt][r] * inv);
            *(uint2*)(orow + dt * 16 + quad * 4) = pk.u;
        }
    }
}

// ---------------------------------------------------------------- head FC1: (8,768)@(768,3072)+relu
__global__ __launch_bounds__(256) void fc1_kernel(
    const float* __restrict__ A, const float* __restrict__ W,
    const float* __restrict__ bias, float* __restrict__ out)
{
    __shared__ float sa[D_MODEL];
    int row = blockIdx.x, t = threadIdx.x;
    for (int i = t; i < D_MODEL; i += 256) sa[i] = A[(size_t)row * D_MODEL + i];
    __syncthreads();
    int col = blockIdx.y * 256 + t;
    float s = 0.f;
    #pragma unroll 8
    for (int kk = 0; kk < D_MODEL; kk++) s = fmaf(sa[kk], W[(size_t)kk * DFF + col], s);
    s += bias[col];
    out[(size_t)row * DFF + col] = fmaxf(s, 0.f);
}

// ---------------------------------------------------------------- head FC2: (8,3072)@(3072,16)
__global__ __launch_bounds__(256) void fc2_kernel(
    const float* __restrict__ A, const float* __restrict__ W,
    const float* __restrict__ bias, float* __restrict__ out)
{
    __shared__ float wred[4][NCLS];
    int row = blockIdx.x, t = threadIdx.x;
    int wave = t >> 6, lane = t & 63;
    const float* a = A + (size_t)row * DFF;
    float acc[NCLS];
    #pragma unroll
    for (int c = 0; c < NCLS; c++) acc[c] = 0.f;
    for (int kk = t; kk < DFF; kk += 256) {
        float av = a[kk];
        const float4* wr = (const float4*)(W + (size_t)kk * NCLS);
        float4 w0 = wr[0], w1 = wr[1], w2 = wr[2], w3 = wr[3];
        acc[0]  = fmaf(av, w0.x, acc[0]);  acc[1]  = fmaf(av, w0.y, acc[1]);
        acc[2]  = fmaf(av, w0.z, acc[2]);  acc[3]  = fmaf(av, w0.w, acc[3]);
        acc[4]  = fmaf(av, w1.x, acc[4]);  acc[5]  = fmaf(av, w1.y, acc[5]);
        acc[6]  = fmaf(av, w1.z, acc[6]);  acc[7]  = fmaf(av, w1.w, acc[7]);
        acc[8]  = fmaf(av, w2.x, acc[8]);  acc[9]  = fmaf(av, w2.y, acc[9]);
        acc[10] = fmaf(av, w2.z, acc[10]); acc[11] = fmaf(av, w2.w, acc[11]);
        acc[12] = fmaf(av, w3.x, acc[12]); acc[13] = fmaf(av, w3.y, acc[13]);
        acc[14] = fmaf(av, w3.z, acc[14]); acc[15] = fmaf(av, w3.w, acc[15]);
    }
    #pragma unroll
    for (int c = 0; c < NCLS; c++)
        #pragma unroll
        for (int off = 32; off; off >>= 1) acc[c] += __shfl_down(acc[c], off);
    if (lane == 0)
        #pragma unroll
        for (int c = 0; c < NCLS; c++) wred[wave][c] = acc[c];
    __syncthreads();
    if (t < NCLS)
        out[row * NCLS + t] = wred[0][t] + wred[1][t] + wred[2][t] + wred[3][t] + bias[t];
}

// ---------------------------------------------------------------- launch
extern "C" void kernel_launch(void* const* d_in, const int* in_sizes, int n_in,
                              void* d_out, int out_size, void* d_ws, size_t ws_size,
                              hipStream_t stream)
{
    const int*   x     = (const int*)  d_in[0];
    const int*   amask = (const int*)  d_in[1];
    const float* tok   = (const float*)d_in[2];
    const float* pos   = (const float*)d_in[3];
    const float* Wq    = (const float*)d_in[4];
    const float* Wk    = (const float*)d_in[5];
    const float* Wv    = (const float*)d_in[6];
    const float* Wo    = (const float*)d_in[7];
    const float* bo    = (const float*)d_in[8];
    const float* ln1w  = (const float*)d_in[9];
    const float* ln1b  = (const float*)d_in[10];
    const float* ln2w  = (const float*)d_in[11];
    const float* ln2b  = (const float*)d_in[12];
    const float* W1    = (const float*)d_in[13];
    const float* b1    = (const float*)d_in[14];
    const float* W2    = (const float*)d_in[15];
    const float* b2    = (const float*)d_in[16];
    const float* lnfw  = (const float*)d_in[17];
    const float* lnfb  = (const float*)d_in[18];
    const float* cW1   = (const float*)d_in[19];
    const float* cb1   = (const float*)d_in[20];
    const float* cW2   = (const float*)d_in[21];
    const float* cb2   = (const float*)d_in[22];

    char* base = (char*)d_ws;
    const size_t MD = (size_t)MROWS * D_MODEL;
    float* h = (float*)base;                         base += MD * 4;
    __hip_bfloat16* xn = (__hip_bfloat16*)base;      base += MD * 2;
    __hip_bfloat16* qb = (__hip_bfloat16*)base;      base += MD * 2;
    __hip_bfloat16* kb = (__hip_bfloat16*)base;      base += MD * 2;
    __hip_bfloat16* vb = (__hip_bfloat16*)base;      base += MD * 2;   // holds V^T (bh,e,s)
    __hip_bfloat16* vT = (__hip_bfloat16*)base;      base += MD * 2;   // unused (kept for layout)
    __hip_bfloat16* ff = (__hip_bfloat16*)base;      base += (size_t)MROWS * DFF * 2;
    float* lnf = (float*)base;                       base += (size_t)NB * D_MODEL * 4;
    float* cls = (float*)base;                       base += (size_t)NB * DFF * 4;
    __hip_bfloat16* wQKV = (__hip_bfloat16*)base;    base += (size_t)NLAYER * 3 * D_MODEL * D_MODEL * 2;
    __hip_bfloat16* wTo = (__hip_bfloat16*)base;     base += (size_t)NLAYER * D_MODEL * D_MODEL * 2;
    __hip_bfloat16* wT1 = (__hip_bfloat16*)base;     base += (size_t)NLAYER * D_MODEL * DFF * 2;
    __hip_bfloat16* wT2 = (__hip_bfloat16*)base;     base += (size_t)NLAYER * DFF * D_MODEL * 2;
    (void)vT;

    const size_t SQW = (size_t)D_MODEL * D_MODEL;
    const size_t SFF = (size_t)D_MODEL * DFF;

    convw_kernel<1><<<dim3(12,12,4), 256, 0, stream>>>(Wq, wQKV + 0 * SQW, D_MODEL, D_MODEL, SQW, 3 * SQW);
    convw_kernel<1><<<dim3(12,12,4), 256, 0, stream>>>(Wk, wQKV + 1 * SQW, D_MODEL, D_MODEL, SQW, 3 * SQW);
    convw_kernel<1><<<dim3(12,12,4), 256, 0, stream>>>(Wv, wQKV + 2 * SQW, D_MODEL, D_MODEL, SQW, 3 * SQW);
    convw_kernel<0><<<dim3(12,12,4), 256, 0, stream>>>(Wo, wTo, D_MODEL, D_MODEL, SQW, SQW);
    convw_kernel<0><<<dim3(12,48,4), 256, 0, stream>>>(W1, wT1, D_MODEL, DFF, SFF, SFF);
    convw_kernel<0><<<dim3(48,12,4), 256, 0, stream>>>(W2, wT2, DFF, D_MODEL, SFF, SFF);

    embed_kernel<<<MROWS / 4, 256, 0, stream>>>(x, tok, pos, h);

    dim3 gQKV(MROWS / 128, (3 * D_MODEL) / 128);
    dim3 gDS(MROWS / 128, D_MODEL / 128, 2);   // split-K=2
    dim3 gF(MROWS / 128, DFF / 128);
    for (int l = 0; l < NLAYER; l++) {
        ln_kernel<1><<<MROWS / 4, 256, 0, stream>>>(h, ln1w + l * D_MODEL, ln1b + l * D_MODEL, xn, 1, 0);
        gemm128<1><<<gQKV, 512, 0, stream>>>(xn, wQKV + l * 3 * SQW, nullptr, nullptr, qb, MROWS, 3 * D_MODEL, D_MODEL, 0);
        attn_mfma_kernel<<<NB * NHEAD * 4, 256, 0, stream>>>(qb, kb, vb, amask, xn);
        gemm128<3><<<gDS, 512, 0, stream>>>(xn, wTo + l * SQW, bo + l * D_MODEL, nullptr, h, MROWS, D_MODEL, D_MODEL, 0);
        ln_kernel<1><<<MROWS / 4, 256, 0, stream>>>(h, ln2w + l * D_MODEL, ln2b + l * D_MODEL, xn, 1, 0);
        gemm128<2><<<gF, 512, 0, stream>>>(xn, wT1 + l * SFF, b1 + l * DFF, nullptr, ff, MROWS, DFF, D_MODEL, 1);
        gemm128<3><<<gDS, 512, 0, stream>>>(ff, wT2 + l * SFF, b2 + l * D_MODEL, nullptr, h, MROWS, D_MODEL, DFF, 0);
    }
    ln_kernel<0><<<NB / 4, 256, 0, stream>>>(h, lnfw, lnfb, lnf, SEQ, SEQ - 1);
    fc1_kernel<<<dim3(NB, DFF / 256), 256, 0, stream>>>(lnf, cW1, cb1, cls);
    fc2_kernel<<<NB, 256, 0, stream>>>(cls, cW2, cb2, (float*)d_out);
}